// Round 1
// baseline (1332.247 us; speedup 1.0000x reference)
//
#include <hip/hip_runtime.h>

// Attention + LoRA fused pipeline, bf16-MFMA strategy.
// ws layout (needs ~195.3 MiB):
//   Aq   bf16 [4096][4160]  = x | SCALE*xA_qkv | 0
//   Wqkv bf16 [6144][4160]  = [wq;wk;wv] | lora_b blocks | 0
//   Wo   bf16 [4096][4160]  = wo | lora_wo_b | 0
//   QKV  bf16 [4096][6144]  = projection output (roped in place)
//   Ao   bf16 [4096][4160]  = attn_out | SCALE*xA_o | 0
//   xA   f32  [4096][64]    = x @ [Aq;Ak;Av;Ao]^T

typedef __attribute__((ext_vector_type(8))) short short8;
typedef __attribute__((ext_vector_type(4))) float f32x4;

#define LORA_SCALE 2.0f
#define INV_SQRT_HD 0.08838834764831845f

static __device__ __forceinline__ unsigned short f2bf(float f) {
  union { float f; unsigned int u; } v; v.f = f;
  unsigned int r = (v.u + 0x7fffu + ((v.u >> 16) & 1u)) >> 16;
  return (unsigned short)r;
}
static __device__ __forceinline__ float bf2f(unsigned short h) {
  union { unsigned int u; float f; } v; v.u = ((unsigned int)h) << 16;
  return v.f;
}

// ---------------------------------------------------------------- GEMM
// C[m,n] = sum_k A[m,k]*B[n,k], A:(Mx K) bf16 row-major, B:(N x K) bf16 row-major.
// 128x128 tile, BK=64, 4 waves (2x2), global_load_lds width 16. K % 64 == 0.
template <int BF16OUT>
__global__ __launch_bounds__(256, 2) void gemm_kernel(
    const unsigned short* __restrict__ A,
    const unsigned short* __restrict__ B,
    void* __restrict__ C, int K, int ldc)
{
  __shared__ unsigned short As[128 * 64];
  __shared__ unsigned short Bs[128 * 64];
  const int tid = threadIdx.x;
  const int w = tid >> 6, l = tid & 63;
  const int l15 = l & 15, lhi = l >> 4;
  const int m0 = blockIdx.y * 128, n0 = blockIdx.x * 128;
  const int wm = (w >> 1) * 64, wn = (w & 1) * 64;

  const f32x4 vzero = {0.f, 0.f, 0.f, 0.f};
  f32x4 acc[4][4];
#pragma unroll
  for (int i = 0; i < 4; ++i)
#pragma unroll
    for (int j = 0; j < 4; ++j) acc[i][j] = vzero;

  const unsigned short* ga = A + (size_t)(m0 + (tid >> 3)) * K + (tid & 7) * 8;
  const unsigned short* gb = B + (size_t)(n0 + (tid >> 3)) * K + (tid & 7) * 8;
  const int nk = K >> 6;
  for (int kt = 0; kt < nk; ++kt) {
#pragma unroll
    for (int it = 0; it < 4; ++it) {
      __builtin_amdgcn_global_load_lds(
          (const unsigned int __attribute__((address_space(1)))*)(ga + (size_t)it * 32 * K),
          (unsigned int __attribute__((address_space(3)))*)((char*)As + it * 4096 + w * 1024),
          16, 0, 0);
      __builtin_amdgcn_global_load_lds(
          (const unsigned int __attribute__((address_space(1)))*)(gb + (size_t)it * 32 * K),
          (unsigned int __attribute__((address_space(3)))*)((char*)Bs + it * 4096 + w * 1024),
          16, 0, 0);
    }
    ga += 64; gb += 64;
    __syncthreads();
#pragma unroll
    for (int kc = 0; kc < 2; ++kc) {
      short8 af[4], bfr[4];
#pragma unroll
      for (int i = 0; i < 4; ++i) {
        af[i]  = *(const short8*)&As[(wm + i * 16 + l15) * 64 + kc * 32 + lhi * 8];
        bfr[i] = *(const short8*)&Bs[(wn + i * 16 + l15) * 64 + kc * 32 + lhi * 8];
      }
#pragma unroll
      for (int mi = 0; mi < 4; ++mi)
#pragma unroll
        for (int ni = 0; ni < 4; ++ni)
          acc[mi][ni] = __builtin_amdgcn_mfma_f32_16x16x32_bf16(af[mi], bfr[ni], acc[mi][ni], 0, 0, 0);
    }
    __syncthreads();
  }
#pragma unroll
  for (int mi = 0; mi < 4; ++mi)
#pragma unroll
    for (int ni = 0; ni < 4; ++ni)
#pragma unroll
      for (int j = 0; j < 4; ++j) {
        size_t row = (size_t)(m0 + wm + mi * 16 + lhi * 4 + j);
        size_t col = (size_t)(n0 + wn + ni * 16 + l15);
        if (BF16OUT) ((unsigned short*)C)[row * ldc + col] = f2bf(acc[mi][ni][j]);
        else         ((float*)C)[row * ldc + col] = acc[mi][ni][j];
      }
}

// ---------------------------------------------------------------- flash attention
// grid (16 qtiles, 32 heads, 2 batch), 256 thr. Q-tile 128 (32 rows/wave), KV tile 64.
__global__ __launch_bounds__(256, 2) void flash_kernel(
    const unsigned short* __restrict__ qkv,  // [4096][6144]: q|k|v (roped)
    unsigned short* __restrict__ outA)       // Ao [4096][4160], cols 0..4095
{
  __shared__ unsigned short Ks[64 * 136];   // K tile [kv][d], pad 136
  __shared__ unsigned short Vt[128 * 72];   // V^T tile [d][kv], pad 72
  __shared__ unsigned short Ps[4][32 * 72]; // per-wave P [q][kv], pad 72
  const int tid = threadIdx.x;
  const int w = tid >> 6, l = tid & 63;
  const int l15 = l & 15, lhi = l >> 4;
  const int qt = blockIdx.x, h = blockIdx.y, b = blockIdx.z;
  const int q0 = qt * 128;
  const int qw0 = q0 + w * 32;
  const int kh = h >> 2;
  const size_t rowb = (size_t)b * 2048;

  short8 qf[2][4];
#pragma unroll
  for (int mf = 0; mf < 2; ++mf)
#pragma unroll
    for (int kc = 0; kc < 4; ++kc)
      qf[mf][kc] = *(const short8*)&qkv[(rowb + qw0 + mf * 16 + l15) * 6144 + h * 128 + kc * 32 + lhi * 8];

  const f32x4 vzero = {0.f, 0.f, 0.f, 0.f};
  f32x4 po[2][8];
  float mrun[2][4], lrun[2][4];
#pragma unroll
  for (int mf = 0; mf < 2; ++mf) {
#pragma unroll
    for (int df = 0; df < 8; ++df) po[mf][df] = vzero;
#pragma unroll
    for (int j = 0; j < 4; ++j) { mrun[mf][j] = -1e30f; lrun[mf][j] = 0.f; }
  }

  const int nt = (q0 >> 6) + 2;
  for (int t = 0; t < nt; ++t) {
    const int kv0 = t * 64;
    // stage K (row-major, pad 136) and V^T (pad 72, rotated write order: 2-way banks)
#pragma unroll
    for (int it = 0; it < 4; ++it) {
      int idx = it * 256 + tid;
      int r = idx >> 4, g = idx & 15;
      const size_t gro = (rowb + kv0 + r) * 6144 + kh * 128 + g * 8;
      *(short8*)&Ks[r * 136 + g * 8] = *(const short8*)&qkv[gro + 4096];
      short8 vv = *(const short8*)&qkv[gro + 5120];
#pragma unroll
      for (int e = 0; e < 8; ++e) {
        int ee = (e + g) & 7;
        Vt[(g * 8 + ee) * 72 + r] = (unsigned short)vv[ee];
      }
    }
    __syncthreads();
    if (kv0 <= qw0 + 31) {
      // S = Q K^T
      f32x4 sa[2][4];
#pragma unroll
      for (int mf = 0; mf < 2; ++mf)
#pragma unroll
        for (int nf = 0; nf < 4; ++nf) sa[mf][nf] = vzero;
#pragma unroll
      for (int kc = 0; kc < 4; ++kc) {
        short8 kf[4];
#pragma unroll
        for (int nf = 0; nf < 4; ++nf)
          kf[nf] = *(const short8*)&Ks[(nf * 16 + l15) * 136 + kc * 32 + lhi * 8];
#pragma unroll
        for (int mf = 0; mf < 2; ++mf)
#pragma unroll
          for (int nf = 0; nf < 4; ++nf)
            sa[mf][nf] = __builtin_amdgcn_mfma_f32_16x16x32_bf16(qf[mf][kc], kf[nf], sa[mf][nf], 0, 0, 0);
      }
      const bool diag = (kv0 + 63) > qw0;
#pragma unroll
      for (int mf = 0; mf < 2; ++mf) {
#pragma unroll
        for (int nf = 0; nf < 4; ++nf)
#pragma unroll
          for (int j = 0; j < 4; ++j) {
            float v = sa[mf][nf][j] * INV_SQRT_HD;
            if (diag) {
              int kvc = kv0 + nf * 16 + l15;
              int qr  = qw0 + mf * 16 + lhi * 4 + j;
              if (kvc > qr) v = -1e30f;
            }
            sa[mf][nf][j] = v;
          }
        // online softmax, rows live in 16-lane groups
#pragma unroll
        for (int j = 0; j < 4; ++j) {
          float rm = fmaxf(fmaxf(sa[mf][0][j], sa[mf][1][j]), fmaxf(sa[mf][2][j], sa[mf][3][j]));
#pragma unroll
          for (int d = 1; d < 16; d <<= 1) rm = fmaxf(rm, __shfl_xor(rm, d));
          float mnew = fmaxf(mrun[mf][j], rm);
          float sc = __expf(mrun[mf][j] - mnew);
          float rs = 0.f;
#pragma unroll
          for (int nf = 0; nf < 4; ++nf) {
            float p = __expf(sa[mf][nf][j] - mnew);
            sa[mf][nf][j] = p;
            rs += p;
          }
#pragma unroll
          for (int d = 1; d < 16; d <<= 1) rs += __shfl_xor(rs, d);
          lrun[mf][j] = lrun[mf][j] * sc + rs;
          mrun[mf][j] = mnew;
#pragma unroll
          for (int df = 0; df < 8; ++df) po[mf][df][j] *= sc;
        }
#pragma unroll
        for (int j = 0; j < 4; ++j)
#pragma unroll
          for (int nf = 0; nf < 4; ++nf)
            Ps[w][(mf * 16 + lhi * 4 + j) * 72 + nf * 16 + l15] = f2bf(sa[mf][nf][j]);
      }
      // O += P V
#pragma unroll
      for (int kc2 = 0; kc2 < 2; ++kc2) {
        short8 pf[2];
#pragma unroll
        for (int mf = 0; mf < 2; ++mf)
          pf[mf] = *(const short8*)&Ps[w][(mf * 16 + l15) * 72 + kc2 * 32 + lhi * 8];
#pragma unroll
        for (int df = 0; df < 8; ++df) {
          short8 vf = *(const short8*)&Vt[(df * 16 + l15) * 72 + kc2 * 32 + lhi * 8];
#pragma unroll
          for (int mf = 0; mf < 2; ++mf)
            po[mf][df] = __builtin_amdgcn_mfma_f32_16x16x32_bf16(pf[mf], vf, po[mf][df], 0, 0, 0);
        }
      }
    }
    __syncthreads();
  }
#pragma unroll
  for (int mf = 0; mf < 2; ++mf)
#pragma unroll
    for (int df = 0; df < 8; ++df)
#pragma unroll
      for (int j = 0; j < 4; ++j) {
        size_t q = (size_t)(qw0 + mf * 16 + lhi * 4 + j);
        int d = df * 16 + l15;
        outA[(rowb + q) * 4160 + h * 128 + d] = f2bf(po[mf][df][j] / lrun[mf][j]);
      }
}

// ---------------------------------------------------------------- aux kernels
__global__ void convert_x_kernel(const float* __restrict__ x, unsigned short* __restrict__ Aq)
{
  int idx = blockIdx.x * 256 + threadIdx.x;  // 4096*512
  int m = idx >> 9;
  int c8 = (idx & 511) * 8;
  f32x4 a = *(const f32x4*)&x[(size_t)m * 4096 + c8];
  f32x4 b2 = *(const f32x4*)&x[(size_t)m * 4096 + c8 + 4];
  short8 o;
#pragma unroll
  for (int e = 0; e < 4; ++e) { o[e] = (short)f2bf(a[e]); o[4 + e] = (short)f2bf(b2[e]); }
  *(short8*)&Aq[(size_t)m * 4160 + c8] = o;
}

__global__ void build_wqkv_kernel(
    const float* __restrict__ wq, const float* __restrict__ wk, const float* __restrict__ wv,
    const float* __restrict__ bq, const float* __restrict__ bk, const float* __restrict__ bv,
    unsigned short* __restrict__ W)
{
  int idx = blockIdx.x * 256 + threadIdx.x;  // 6144*520
  int n = idx / 520;
  int c8 = (idx - n * 520) * 8;
  short8 o;
  if (c8 < 4096) {
    const float* src = n < 4096 ? wq + (size_t)n * 4096
                     : n < 5120 ? wk + (size_t)(n - 4096) * 4096
                                : wv + (size_t)(n - 5120) * 4096;
    f32x4 a = *(const f32x4*)&src[c8];
    f32x4 b2 = *(const f32x4*)&src[c8 + 4];
#pragma unroll
    for (int e = 0; e < 4; ++e) { o[e] = (short)f2bf(a[e]); o[4 + e] = (short)f2bf(b2[e]); }
  } else {
#pragma unroll
    for (int e = 0; e < 8; ++e) {
      int j = c8 + e - 4096;
      float v = 0.f;
      if (n < 4096)      { if (j < 16)            v = bq[(size_t)n * 16 + j]; }
      else if (n < 5120) { if (j >= 16 && j < 32) v = bk[(size_t)(n - 4096) * 16 + (j - 16)]; }
      else               { if (j >= 32 && j < 48) v = bv[(size_t)(n - 5120) * 16 + (j - 32)]; }
      o[e] = (short)f2bf(v);
    }
  }
  *(short8*)&W[(size_t)n * 4160 + c8] = o;
}

__global__ void build_wo_kernel(const float* __restrict__ wo, const float* __restrict__ bo,
                                unsigned short* __restrict__ W)
{
  int idx = blockIdx.x * 256 + threadIdx.x;  // 4096*520
  int n = idx / 520;
  int c8 = (idx - n * 520) * 8;
  short8 o;
  if (c8 < 4096) {
    const float* src = wo + (size_t)n * 4096 + c8;
    f32x4 a = *(const f32x4*)&src[0];
    f32x4 b2 = *(const f32x4*)&src[4];
#pragma unroll
    for (int e = 0; e < 4; ++e) { o[e] = (short)f2bf(a[e]); o[4 + e] = (short)f2bf(b2[e]); }
  } else {
#pragma unroll
    for (int e = 0; e < 8; ++e) {
      int j = c8 + e - 4096;
      float v = (j < 16) ? bo[(size_t)n * 16 + j] : 0.f;
      o[e] = (short)f2bf(v);
    }
  }
  *(short8*)&W[(size_t)n * 4160 + c8] = o;
}

// xA[m][0..63] = x[m] . A_row  (A = lora_wq_a|wk|wv|wo, 16 rows each), exact fp32.
__global__ __launch_bounds__(256) void xa_kernel(
    const float* __restrict__ x,
    const float* __restrict__ aq, const float* __restrict__ ak,
    const float* __restrict__ av, const float* __restrict__ ao,
    float* __restrict__ xA)
{
  __shared__ float xs[16][512];
  const int tid = threadIdx.x;
  const int m0 = blockIdx.x * 16;   // 256 blocks
  const int r = tid >> 4;
  const int ob = (tid & 15) * 4;
  const float* As = ob < 16 ? aq : ob < 32 ? ak : ob < 48 ? av : ao;
  const int oo = ob & 15;
  float a0 = 0.f, a1 = 0.f, a2 = 0.f, a3 = 0.f;
  for (int kc = 0; kc < 8; ++kc) {
    __syncthreads();
#pragma unroll
    for (int it = 0; it < 8; ++it) {
      int lin = it * 1024 + tid * 4;
      int rr = lin >> 9, cc = lin & 511;
      *(f32x4*)&xs[rr][cc] = *(const f32x4*)&x[(size_t)(m0 + rr) * 4096 + kc * 512 + cc];
    }
    __syncthreads();
    const float* A0 = As + (size_t)oo * 4096 + kc * 512;
    const float* A1 = A0 + 4096;
    const float* A2 = A0 + 8192;
    const float* A3 = A0 + 12288;
#pragma unroll 4
    for (int k = 0; k < 512; k += 4) {
      f32x4 xv = *(const f32x4*)&xs[r][k];
      f32x4 v0 = *(const f32x4*)&A0[k];
      f32x4 v1 = *(const f32x4*)&A1[k];
      f32x4 v2 = *(const f32x4*)&A2[k];
      f32x4 v3 = *(const f32x4*)&A3[k];
#pragma unroll
      for (int e = 0; e < 4; ++e) {
        a0 += xv[e] * v0[e]; a1 += xv[e] * v1[e];
        a2 += xv[e] * v2[e]; a3 += xv[e] * v3[e];
      }
    }
  }
  f32x4 res; res[0] = a0; res[1] = a1; res[2] = a2; res[3] = a3;
  *(f32x4*)&xA[(size_t)(m0 + r) * 64 + ob] = res;
}

__global__ void build_a_tail_kernel(const float* __restrict__ xA,
                                    unsigned short* __restrict__ Aq,
                                    unsigned short* __restrict__ Ao)
{
  int m = blockIdx.x * 256 + threadIdx.x;  // 4096
  const float* src = xA + (size_t)m * 64;
  unsigned short* d1 = Aq + (size_t)m * 4160 + 4096;
  unsigned short* d2 = Ao + (size_t)m * 4160 + 4096;
#pragma unroll
  for (int j = 0; j < 64; ++j) d1[j] = f2bf(j < 48 ? LORA_SCALE * src[j] : 0.f);
#pragma unroll
  for (int j = 0; j < 64; ++j) d2[j] = f2bf(j < 16 ? LORA_SCALE * src[48 + j] : 0.f);
}

// In-place RoPE on q|k sections of QKV (cols 0..5119), 8 cols (4 pairs) per thread.
__global__ void rope_kernel(unsigned short* __restrict__ qkv,
                            const float* __restrict__ fcos,
                            const float* __restrict__ fsin)
{
  int idx = blockIdx.x * 256 + threadIdx.x;  // 4096*640
  int m = idx / 640;
  int c8 = (idx - m * 640) * 8;
  int s = m & 2047;
  int i0 = (c8 & 127) >> 1;
  unsigned short* p = qkv + (size_t)m * 6144 + c8;
  short8 v = *(short8*)p;
  f32x4 c = *(const f32x4*)&fcos[s * 64 + i0];
  f32x4 sn = *(const f32x4*)&fsin[s * 64 + i0];
  short8 o;
#pragma unroll
  for (int pr = 0; pr < 4; ++pr) {
    float re = bf2f((unsigned short)v[2 * pr]);
    float im = bf2f((unsigned short)v[2 * pr + 1]);
    o[2 * pr]     = (short)f2bf(re * c[pr] - im * sn[pr]);
    o[2 * pr + 1] = (short)f2bf(re * sn[pr] + im * c[pr]);
  }
  *(short8*)p = o;
}

// ---------------------------------------------------------------- launch
extern "C" void kernel_launch(void* const* d_in, const int* in_sizes, int n_in,
                              void* d_out, int out_size, void* d_ws, size_t ws_size,
                              hipStream_t stream) {
  (void)in_sizes; (void)n_in; (void)out_size; (void)ws_size;
  const float* x    = (const float*)d_in[0];
  const float* w_q  = (const float*)d_in[1];
  const float* w_k  = (const float*)d_in[2];
  const float* w_v  = (const float*)d_in[3];
  const float* w_o  = (const float*)d_in[4];
  const float* la_q = (const float*)d_in[5];
  const float* lb_q = (const float*)d_in[6];
  const float* la_k = (const float*)d_in[7];
  const float* lb_k = (const float*)d_in[8];
  const float* la_v = (const float*)d_in[9];
  const float* lb_v = (const float*)d_in[10];
  const float* la_o = (const float*)d_in[11];
  const float* lb_o = (const float*)d_in[12];
  // d_in[13], d_in[14]: zero caches (start_pos=0, fully overwritten) — unused
  const float* fcos = (const float*)d_in[15];
  const float* fsin = (const float*)d_in[16];
  // d_in[17] mask (causal, applied analytically), d_in[18] start_pos=0 — unused

  unsigned short* Aq   = (unsigned short*)d_ws;              // 4096*4160
  unsigned short* Wqkv = Aq + (size_t)4096 * 4160;           // 6144*4160
  unsigned short* Wo   = Wqkv + (size_t)6144 * 4160;         // 4096*4160
  unsigned short* QKV  = Wo + (size_t)4096 * 4160;           // 4096*6144
  unsigned short* Ao   = QKV + (size_t)4096 * 6144;          // 4096*4160
  float* xA            = (float*)(Ao + (size_t)4096 * 4160); // 4096*64 f32

  dim3 blk(256);
  build_wqkv_kernel<<<12480, blk, 0, stream>>>(w_q, w_k, w_v, lb_q, lb_k, lb_v, Wqkv);
  build_wo_kernel<<<8320, blk, 0, stream>>>(w_o, lb_o, Wo);
  convert_x_kernel<<<8192, blk, 0, stream>>>(x, Aq);
  xa_kernel<<<256, blk, 0, stream>>>(x, la_q, la_k, la_v, la_o, xA);
  build_a_tail_kernel<<<16, blk, 0, stream>>>(xA, Aq, Ao);
  gemm_kernel<1><<<dim3(48, 32), blk, 0, stream>>>(Aq, Wqkv, QKV, 4160, 6144);
  rope_kernel<<<10240, blk, 0, stream>>>(QKV, fcos, fsin);
  flash_kernel<<<dim3(16, 32, 2), blk, 0, stream>>>(QKV, Ao);
  gemm_kernel<0><<<dim3(32, 32), blk, 0, stream>>>(Ao, Wo, d_out, 4160, 4096);
}

// Round 3
// 936.793 us; speedup vs baseline: 1.4221x; 1.4221x over previous
//
#include <hip/hip_runtime.h>

// Attention + LoRA fused pipeline, bf16-MFMA strategy, round 3.
// q/k/v LoRA folded into weights (exact: both apply to x).
// O-projection LoRA applies to x (NOT attn out!) -> augmented-K GEMM:
//   Ao = [attn_out | SCALE*(x@A_o^T) | 0]  (K=4160),  Wo' = [w_o | B_o | 0].
// ws layout (~193.3 MiB):
//   Wqkv bf16 [6144][4096]
//   Wo   bf16 [4096][4160]
//   Xbf  bf16 [4096][4096]
//   QKV  bf16 [4096][6144]   (roped in place)
//   Ao   bf16 [4096][4160]
//   t    f32  [4096][16]

typedef __attribute__((ext_vector_type(8))) short short8;
typedef __attribute__((ext_vector_type(4))) short short4v;
typedef __attribute__((ext_vector_type(4))) float f32x4;

#define LORA_SCALE 2.0f
#define INV_SQRT_HD 0.08838834764831845f

static __device__ __forceinline__ unsigned short f2bf(float f) {
  union { float f; unsigned int u; } v; v.f = f;
  unsigned int r = (v.u + 0x7fffu + ((v.u >> 16) & 1u)) >> 16;
  return (unsigned short)r;
}
static __device__ __forceinline__ float bf2f(unsigned short h) {
  union { unsigned int u; float f; } v; v.u = ((unsigned int)h) << 16;
  return v.f;
}

// ---------------------------------------------------------------- GEMM
// C[m,n] = sum_k A[m,k]*B[n,k], both bf16 row-major. 128x128 tile, BK=64,
// 4 waves (2x2), global_load_lds width 16. K % 64 == 0.
template <int BF16OUT>
__global__ __launch_bounds__(256, 2) void gemm_kernel(
    const unsigned short* __restrict__ A,
    const unsigned short* __restrict__ B,
    void* __restrict__ C, int K, int ldc)
{
  __shared__ unsigned short As[128 * 64];
  __shared__ unsigned short Bs[128 * 64];
  const int tid = threadIdx.x;
  const int w = tid >> 6, l = tid & 63;
  const int l15 = l & 15, lhi = l >> 4;
  const int m0 = blockIdx.y * 128, n0 = blockIdx.x * 128;
  const int wm = (w >> 1) * 64, wn = (w & 1) * 64;

  const f32x4 vzero = {0.f, 0.f, 0.f, 0.f};
  f32x4 acc[4][4];
#pragma unroll
  for (int i = 0; i < 4; ++i)
#pragma unroll
    for (int j = 0; j < 4; ++j) acc[i][j] = vzero;

  const unsigned short* ga = A + (size_t)(m0 + (tid >> 3)) * K + (tid & 7) * 8;
  const unsigned short* gb = B + (size_t)(n0 + (tid >> 3)) * K + (tid & 7) * 8;
  const int nk = K >> 6;
  for (int kt = 0; kt < nk; ++kt) {
#pragma unroll
    for (int it = 0; it < 4; ++it) {
      __builtin_amdgcn_global_load_lds(
          (const unsigned int __attribute__((address_space(1)))*)(ga + (size_t)it * 32 * K),
          (unsigned int __attribute__((address_space(3)))*)((char*)As + it * 4096 + w * 1024),
          16, 0, 0);
      __builtin_amdgcn_global_load_lds(
          (const unsigned int __attribute__((address_space(1)))*)(gb + (size_t)it * 32 * K),
          (unsigned int __attribute__((address_space(3)))*)((char*)Bs + it * 4096 + w * 1024),
          16, 0, 0);
    }
    ga += 64; gb += 64;
    __syncthreads();
#pragma unroll
    for (int kc = 0; kc < 2; ++kc) {
      short8 af[4], bfr[4];
#pragma unroll
      for (int i = 0; i < 4; ++i) {
        af[i]  = *(const short8*)&As[(wm + i * 16 + l15) * 64 + kc * 32 + lhi * 8];
        bfr[i] = *(const short8*)&Bs[(wn + i * 16 + l15) * 64 + kc * 32 + lhi * 8];
      }
#pragma unroll
      for (int mi = 0; mi < 4; ++mi)
#pragma unroll
        for (int ni = 0; ni < 4; ++ni)
          acc[mi][ni] = __builtin_amdgcn_mfma_f32_16x16x32_bf16(af[mi], bfr[ni], acc[mi][ni], 0, 0, 0);
    }
    __syncthreads();
  }
#pragma unroll
  for (int mi = 0; mi < 4; ++mi)
#pragma unroll
    for (int ni = 0; ni < 4; ++ni)
#pragma unroll
      for (int j = 0; j < 4; ++j) {
        size_t row = (size_t)(m0 + wm + mi * 16 + lhi * 4 + j);
        size_t col = (size_t)(n0 + wn + ni * 16 + l15);
        if (BF16OUT) ((unsigned short*)C)[row * ldc + col] = f2bf(acc[mi][ni][j]);
        else         ((float*)C)[row * ldc + col] = acc[mi][ni][j];
      }
}

// ---------------------------------------------------------------- flash attention
// grid (16 qtiles, 32 heads, 2 batch), 256 thr. Q-tile 128 (32 rows/wave), KV tile 64.
__global__ __launch_bounds__(256, 2) void flash_kernel(
    const unsigned short* __restrict__ qkv,  // [4096][6144]: q|k|v (roped)
    unsigned short* __restrict__ outA)       // Ao [4096][4160], cols 0..4095
{
  __shared__ unsigned short Ks[64 * 136];   // K tile [kv][d], pad 136
  __shared__ unsigned short Vt[128 * 72];   // V^T tile [d][kv], pad 72
  __shared__ unsigned short Ps[4][32 * 72]; // per-wave P [q][kv], pad 72
  const int tid = threadIdx.x;
  const int w = tid >> 6, l = tid & 63;
  const int l15 = l & 15, lhi = l >> 4;
  const int qt = blockIdx.x, h = blockIdx.y, b = blockIdx.z;
  const int q0 = qt * 128;
  const int qw0 = q0 + w * 32;
  const int kh = h >> 2;
  const size_t rowb = (size_t)b * 2048;

  short8 qf[2][4];
#pragma unroll
  for (int mf = 0; mf < 2; ++mf)
#pragma unroll
    for (int kc = 0; kc < 4; ++kc)
      qf[mf][kc] = *(const short8*)&qkv[(rowb + qw0 + mf * 16 + l15) * 6144 + h * 128 + kc * 32 + lhi * 8];

  const f32x4 vzero = {0.f, 0.f, 0.f, 0.f};
  f32x4 po[2][8];
  float mrun[2][4], lrun[2][4];
#pragma unroll
  for (int mf = 0; mf < 2; ++mf) {
#pragma unroll
    for (int df = 0; df < 8; ++df) po[mf][df] = vzero;
#pragma unroll
    for (int j = 0; j < 4; ++j) { mrun[mf][j] = -1e30f; lrun[mf][j] = 0.f; }
  }

  const int nt = (q0 >> 6) + 2;
  for (int t = 0; t < nt; ++t) {
    const int kv0 = t * 64;
#pragma unroll
    for (int it = 0; it < 4; ++it) {
      int idx = it * 256 + tid;
      int r = idx >> 4, g = idx & 15;
      const size_t gro = (rowb + kv0 + r) * 6144 + kh * 128 + g * 8;
      *(short8*)&Ks[r * 136 + g * 8] = *(const short8*)&qkv[gro + 4096];
      short8 vv = *(const short8*)&qkv[gro + 5120];
#pragma unroll
      for (int e = 0; e < 8; ++e) {
        int ee = (e + g) & 7;
        Vt[(g * 8 + ee) * 72 + r] = (unsigned short)vv[ee];
      }
    }
    __syncthreads();
    if (kv0 <= qw0 + 31) {
      f32x4 sa[2][4];
#pragma unroll
      for (int mf = 0; mf < 2; ++mf)
#pragma unroll
        for (int nf = 0; nf < 4; ++nf) sa[mf][nf] = vzero;
#pragma unroll
      for (int kc = 0; kc < 4; ++kc) {
        short8 kf[4];
#pragma unroll
        for (int nf = 0; nf < 4; ++nf)
          kf[nf] = *(const short8*)&Ks[(nf * 16 + l15) * 136 + kc * 32 + lhi * 8];
#pragma unroll
        for (int mf = 0; mf < 2; ++mf)
#pragma unroll
          for (int nf = 0; nf < 4; ++nf)
            sa[mf][nf] = __builtin_amdgcn_mfma_f32_16x16x32_bf16(qf[mf][kc], kf[nf], sa[mf][nf], 0, 0, 0);
      }
      const bool diag = (kv0 + 63) > qw0;
#pragma unroll
      for (int mf = 0; mf < 2; ++mf) {
#pragma unroll
        for (int nf = 0; nf < 4; ++nf)
#pragma unroll
          for (int j = 0; j < 4; ++j) {
            float v = sa[mf][nf][j] * INV_SQRT_HD;
            if (diag) {
              int kvc = kv0 + nf * 16 + l15;
              int qr  = qw0 + mf * 16 + lhi * 4 + j;
              if (kvc > qr) v = -1e30f;
            }
            sa[mf][nf][j] = v;
          }
#pragma unroll
        for (int j = 0; j < 4; ++j) {
          float rm = fmaxf(fmaxf(sa[mf][0][j], sa[mf][1][j]), fmaxf(sa[mf][2][j], sa[mf][3][j]));
#pragma unroll
          for (int d = 1; d < 16; d <<= 1) rm = fmaxf(rm, __shfl_xor(rm, d));
          float mnew = fmaxf(mrun[mf][j], rm);
          float sc = __expf(mrun[mf][j] - mnew);
          float rs = 0.f;
#pragma unroll
          for (int nf = 0; nf < 4; ++nf) {
            float p = __expf(sa[mf][nf][j] - mnew);
            sa[mf][nf][j] = p;
            rs += p;
          }
#pragma unroll
          for (int d = 1; d < 16; d <<= 1) rs += __shfl_xor(rs, d);
          lrun[mf][j] = lrun[mf][j] * sc + rs;
          mrun[mf][j] = mnew;
#pragma unroll
          for (int df = 0; df < 8; ++df) po[mf][df][j] *= sc;
        }
#pragma unroll
        for (int j = 0; j < 4; ++j)
#pragma unroll
          for (int nf = 0; nf < 4; ++nf)
            Ps[w][(mf * 16 + lhi * 4 + j) * 72 + nf * 16 + l15] = f2bf(sa[mf][nf][j]);
      }
#pragma unroll
      for (int kc2 = 0; kc2 < 2; ++kc2) {
        short8 pf[2];
#pragma unroll
        for (int mf = 0; mf < 2; ++mf)
          pf[mf] = *(const short8*)&Ps[w][(mf * 16 + l15) * 72 + kc2 * 32 + lhi * 8];
#pragma unroll
        for (int df = 0; df < 8; ++df) {
          short8 vf = *(const short8*)&Vt[(df * 16 + l15) * 72 + kc2 * 32 + lhi * 8];
#pragma unroll
          for (int mf = 0; mf < 2; ++mf)
            po[mf][df] = __builtin_amdgcn_mfma_f32_16x16x32_bf16(pf[mf], vf, po[mf][df], 0, 0, 0);
        }
      }
    }
    __syncthreads();
  }
#pragma unroll
  for (int mf = 0; mf < 2; ++mf)
#pragma unroll
    for (int df = 0; df < 8; ++df)
#pragma unroll
      for (int j = 0; j < 4; ++j) {
        size_t q = (size_t)(qw0 + mf * 16 + lhi * 4 + j);
        int d = df * 16 + l15;
        outA[(rowb + q) * 4160 + h * 128 + d] = f2bf(po[mf][df][j] / lrun[mf][j]);
      }
}

// ---------------------------------------------------------------- aux kernels
__global__ void convert_x_kernel(const float* __restrict__ x, unsigned short* __restrict__ Xb)
{
  int idx = blockIdx.x * 256 + threadIdx.x;  // 4096*512
  int m = idx >> 9;
  int c8 = (idx & 511) * 8;
  f32x4 a = *(const f32x4*)&x[(size_t)m * 4096 + c8];
  f32x4 b2 = *(const f32x4*)&x[(size_t)m * 4096 + c8 + 4];
  short8 o;
#pragma unroll
  for (int e = 0; e < 4; ++e) { o[e] = (short)f2bf(a[e]); o[4 + e] = (short)f2bf(b2[e]); }
  *(short8*)&Xb[(size_t)m * 4096 + c8] = o;
}

// W'[n][c] = bf16( w[n][c] + SCALE * sum_r b[n][r] * a[r][c] )   (q/k/v only)
// grid (rows/8, 4096/512), 256 thr.
__global__ __launch_bounds__(256) void fold_kernel(
    const float* __restrict__ w, const float* __restrict__ b,
    const float* __restrict__ a, unsigned short* __restrict__ W)
{
  __shared__ unsigned short als[16][512];
  const int tid = threadIdx.x;
  const int n0 = blockIdx.x * 8;
  const int c0 = blockIdx.y * 512;
#pragma unroll
  for (int it = 0; it < 8; ++it) {
    int flat = it * 1024 + tid * 4;
    int r = flat >> 9, c = flat & 511;
    f32x4 v = *(const f32x4*)&a[(size_t)r * 4096 + c0 + c];
    short4v o;
#pragma unroll
    for (int e = 0; e < 4; ++e) o[e] = (short)f2bf(LORA_SCALE * v[e]);
    *(short4v*)&als[r][c] = o;
  }
  __syncthreads();
  const int n = n0 + (tid >> 5);
  const int cb = (tid & 31) * 16;
  const float* wrow = w + (size_t)n * 4096 + c0 + cb;
  const float* brow = b + (size_t)n * 16;
  float bb[16];
#pragma unroll
  for (int r4 = 0; r4 < 4; ++r4) {
    f32x4 t = *(const f32x4*)&brow[r4 * 4];
#pragma unroll
    for (int e = 0; e < 4; ++e) bb[r4 * 4 + e] = t[e];
  }
  float acc[16];
#pragma unroll
  for (int j4 = 0; j4 < 4; ++j4) {
    f32x4 t = *(const f32x4*)&wrow[j4 * 4];
#pragma unroll
    for (int e = 0; e < 4; ++e) acc[j4 * 4 + e] = t[e];
  }
#pragma unroll
  for (int r = 0; r < 16; ++r) {
    short8 a0 = *(const short8*)&als[r][cb];
    short8 a1 = *(const short8*)&als[r][cb + 8];
    float br = bb[r];
#pragma unroll
    for (int e = 0; e < 8; ++e) {
      acc[e]     += br * bf2f((unsigned short)a0[e]);
      acc[8 + e] += br * bf2f((unsigned short)a1[e]);
    }
  }
  short8 o0, o1;
#pragma unroll
  for (int e = 0; e < 8; ++e) { o0[e] = (short)f2bf(acc[e]); o1[e] = (short)f2bf(acc[8 + e]); }
  unsigned short* dst = W + (size_t)n * 4096 + c0 + cb;
  *(short8*)&dst[0] = o0;
  *(short8*)&dst[8] = o1;
}

// Wo' = [w_o | B_o | 0], row stride 4160.
__global__ void build_wo_kernel(const float* __restrict__ wo, const float* __restrict__ bo,
                                unsigned short* __restrict__ W)
{
  int idx = blockIdx.x * 256 + threadIdx.x;  // 4096*520
  int n = idx / 520;
  int c8 = (idx - n * 520) * 8;
  short8 o;
  if (c8 < 4096) {
    const float* src = wo + (size_t)n * 4096 + c8;
    f32x4 a = *(const f32x4*)&src[0];
    f32x4 b2 = *(const f32x4*)&src[4];
#pragma unroll
    for (int e = 0; e < 4; ++e) { o[e] = (short)f2bf(a[e]); o[4 + e] = (short)f2bf(b2[e]); }
  } else {
#pragma unroll
    for (int e = 0; e < 8; ++e) {
      int j = c8 + e - 4096;
      float v = (j < 16) ? bo[(size_t)n * 16 + j] : 0.f;
      o[e] = (short)f2bf(v);
    }
  }
  *(short8*)&W[(size_t)n * 4160 + c8] = o;
}

// t[m][r] = x[m] . a_o[r]  (fp32, 16 outputs), 4096 blocks x 256 thr.
__global__ __launch_bounds__(256) void t_kernel(
    const float* __restrict__ x, const float* __restrict__ ao, float* __restrict__ t)
{
  __shared__ float red[4][16];
  const int m = blockIdx.x;
  const int tid = threadIdx.x;
  const int w = tid >> 6, l = tid & 63;
  float part[16];
#pragma unroll
  for (int r = 0; r < 16; ++r) part[r] = 0.f;
#pragma unroll
  for (int it = 0; it < 4; ++it) {
    int k = it * 1024 + tid * 4;
    f32x4 xv = *(const f32x4*)&x[(size_t)m * 4096 + k];
#pragma unroll
    for (int r = 0; r < 16; ++r) {
      f32x4 av = *(const f32x4*)&ao[(size_t)r * 4096 + k];
      part[r] += xv[0] * av[0] + xv[1] * av[1] + xv[2] * av[2] + xv[3] * av[3];
    }
  }
#pragma unroll
  for (int d = 1; d < 64; d <<= 1)
#pragma unroll
    for (int r = 0; r < 16; ++r) part[r] += __shfl_xor(part[r], d);
  if (l == 0)
#pragma unroll
    for (int r = 0; r < 16; ++r) red[w][r] = part[r];
  __syncthreads();
  if (tid < 16)
    t[(size_t)m * 16 + tid] = red[0][tid] + red[1][tid] + red[2][tid] + red[3][tid];
}

// Ao tail: cols 4096..4111 = bf16(SCALE*t), 4112..4159 = 0.
__global__ void a_tail_kernel(const float* __restrict__ t, unsigned short* __restrict__ Ao)
{
  int m = blockIdx.x * 256 + threadIdx.x;  // 16 blocks
  const float* src = t + (size_t)m * 16;
  unsigned short* d = Ao + (size_t)m * 4160 + 4096;
  short8 o0, o1, z;
#pragma unroll
  for (int e = 0; e < 8; ++e) {
    o0[e] = (short)f2bf(LORA_SCALE * src[e]);
    o1[e] = (short)f2bf(LORA_SCALE * src[8 + e]);
    z[e] = 0;
  }
  *(short8*)&d[0] = o0;
  *(short8*)&d[8] = o1;
#pragma unroll
  for (int c = 0; c < 6; ++c) *(short8*)&d[16 + c * 8] = z;
}

// In-place RoPE on q|k sections of QKV (cols 0..5119), 8 cols (4 pairs) per thread.
__global__ void rope_kernel(unsigned short* __restrict__ qkv,
                            const float* __restrict__ fcos,
                            const float* __restrict__ fsin)
{
  int idx = blockIdx.x * 256 + threadIdx.x;  // 4096*640
  int m = idx / 640;
  int c8 = (idx - m * 640) * 8;
  int s = m & 2047;
  int i0 = (c8 & 127) >> 1;
  unsigned short* p = qkv + (size_t)m * 6144 + c8;
  short8 v = *(short8*)p;
  f32x4 c = *(const f32x4*)&fcos[s * 64 + i0];
  f32x4 sn = *(const f32x4*)&fsin[s * 64 + i0];
  short8 o;
#pragma unroll
  for (int pr = 0; pr < 4; ++pr) {
    float re = bf2f((unsigned short)v[2 * pr]);
    float im = bf2f((unsigned short)v[2 * pr + 1]);
    o[2 * pr]     = (short)f2bf(re * c[pr] - im * sn[pr]);
    o[2 * pr + 1] = (short)f2bf(re * sn[pr] + im * c[pr]);
  }
  *(short8*)p = o;
}

// ---------------------------------------------------------------- launch
extern "C" void kernel_launch(void* const* d_in, const int* in_sizes, int n_in,
                              void* d_out, int out_size, void* d_ws, size_t ws_size,
                              hipStream_t stream) {
  (void)in_sizes; (void)n_in; (void)out_size; (void)ws_size;
  const float* x    = (const float*)d_in[0];
  const float* w_q  = (const float*)d_in[1];
  const float* w_k  = (const float*)d_in[2];
  const float* w_v  = (const float*)d_in[3];
  const float* w_o  = (const float*)d_in[4];
  const float* la_q = (const float*)d_in[5];
  const float* lb_q = (const float*)d_in[6];
  const float* la_k = (const float*)d_in[7];
  const float* lb_k = (const float*)d_in[8];
  const float* la_v = (const float*)d_in[9];
  const float* lb_v = (const float*)d_in[10];
  const float* la_o = (const float*)d_in[11];
  const float* lb_o = (const float*)d_in[12];
  // d_in[13..14]: zero caches (start_pos=0) — unused
  const float* fcos = (const float*)d_in[15];
  const float* fsin = (const float*)d_in[16];
  // d_in[17] mask (causal, analytic), d_in[18] start_pos=0 — unused

  unsigned short* Wqkv = (unsigned short*)d_ws;              // 6144*4096
  unsigned short* Wo   = Wqkv + (size_t)6144 * 4096;         // 4096*4160
  unsigned short* Xbf  = Wo + (size_t)4096 * 4160;           // 4096*4096
  unsigned short* QKV  = Xbf + (size_t)4096 * 4096;          // 4096*6144
  unsigned short* Ao   = QKV + (size_t)4096 * 6144;          // 4096*4160
  float* t             = (float*)(Ao + (size_t)4096 * 4160); // 4096*16 f32

  dim3 blk(256);
  fold_kernel<<<dim3(512, 8), blk, 0, stream>>>(w_q, lb_q, la_q, Wqkv);
  fold_kernel<<<dim3(128, 8), blk, 0, stream>>>(w_k, lb_k, la_k, Wqkv + (size_t)4096 * 4096);
  fold_kernel<<<dim3(128, 8), blk, 0, stream>>>(w_v, lb_v, la_v, Wqkv + (size_t)5120 * 4096);
  build_wo_kernel<<<8320, blk, 0, stream>>>(w_o, lb_o, Wo);
  convert_x_kernel<<<8192, blk, 0, stream>>>(x, Xbf);
  t_kernel<<<4096, blk, 0, stream>>>(x, la_o, t);
  a_tail_kernel<<<16, blk, 0, stream>>>(t, Ao);
  gemm_kernel<1><<<dim3(48, 32), blk, 0, stream>>>(Xbf, Wqkv, QKV, 4096, 6144);
  rope_kernel<<<10240, blk, 0, stream>>>(QKV, fcos, fsin);
  flash_kernel<<<dim3(16, 32, 2), blk, 0, stream>>>(QKV, Ao);
  gemm_kernel<0><<<dim3(32, 32), blk, 0, stream>>>(Ao, Wo, d_out, 4160, 4096);
}